// Round 8
// baseline (312.266 us; speedup 1.0000x reference)
//
#include <hip/hip_runtime.h>

#define N_NODES 50000
#define MP      50048        // N_NODES padded to multiple of 128
#define N_EDGES 800000
#define NFEAT   512
#define NHID    256
#define NOUT    64

typedef __bf16 bf16x8 __attribute__((ext_vector_type(8)));
typedef float  f32x4  __attribute__((ext_vector_type(4)));

// async global->LDS, 16B per lane. LDS dest = wave-uniform base + lane*16;
// source address is PER-LANE (normal vector-load semantics on the read side).
#define GLOAD_LDS16(g, l) __builtin_amdgcn_global_load_lds(                    \
    (const __attribute__((address_space(1))) void*)(g),                        \
    (__attribute__((address_space(3))) void*)(l), 16, 0, 0)

__device__ __forceinline__ unsigned short f2bf(float f) {
    __bf16 b = (__bf16)f;                       // RNE
    return __builtin_bit_cast(unsigned short, b);
}

__device__ __forceinline__ bf16x8 pack8(float4 a, float4 b) {
    uint4 o;
    o.x = (unsigned)f2bf(a.x) | ((unsigned)f2bf(a.y) << 16);
    o.y = (unsigned)f2bf(a.z) | ((unsigned)f2bf(a.w) << 16);
    o.z = (unsigned)f2bf(b.x) | ((unsigned)f2bf(b.y) << 16);
    o.w = (unsigned)f2bf(b.z) | ((unsigned)f2bf(b.w) << 16);
    return __builtin_bit_cast(bf16x8, o);
}

// ---------------------------------------------------------------------------
// prep: fused rowptr + w1 transpose + w2 transpose + h1 pad zero. 820 blocks.
// ---------------------------------------------------------------------------
__global__ __launch_bounds__(256) void prep(const int* __restrict__ row,
                                            int* __restrict__ rp,
                                            const float* __restrict__ w1,
                                            __bf16* __restrict__ w1t,
                                            const float* __restrict__ w2,
                                            __bf16* __restrict__ w2t,
                                            __bf16* __restrict__ h1) {
    const int b = blockIdx.x, t = threadIdx.x;
    if (b < 196) {
        int r = b * 256 + t;
        if (r <= N_NODES) {
            int lo = 0, hi = N_EDGES;
            while (lo < hi) {
                int mid = (lo + hi) >> 1;
                if (row[mid] < r) lo = mid + 1; else hi = mid;
            }
            rp[r] = lo;
        }
    } else if (b < 708) {
        int o = (b - 196) * 256 + t;          // n = o>>9, k = o&511
        w1t[o] = (__bf16)w1[(size_t)(o & 511) * NHID + (o >> 9)];
    } else if (b < 772) {
        int o = (b - 708) * 256 + t;          // n = o>>8, k = o&255
        w2t[o] = (__bf16)w2[(size_t)(o & 255) * NOUT + (o >> 8)];
    } else {
        int o = (b - 772) * 256 + t;
        h1[(size_t)N_NODES * NHID + o] = (__bf16)0.f;
    }
}

// ---------------------------------------------------------------------------
// GEMM1, barrier-free K-loop: C[MP][256] bf16 = bf16(X fp32) @ w1t[256][512]^T
// Block = 128 rows x 64 cols, 4 waves (32 rows each). B-slab (64 cols x 512 K
// = 64 KB) staged to LDS ONCE in [kt][col][32] layout; single __syncthreads;
// then 16 K-iters with A direct-to-register (1-iter prefetch), ds_read B,
// MFMA — no barriers, no collective vmcnt(0) drains.
// A rows clamped (not guarded): h0 pad rows are never read downstream.
// ---------------------------------------------------------------------------
__global__ __launch_bounds__(256) void gemm1_nb(const float* __restrict__ X,
                                                const __bf16* __restrict__ Bt,
                                                __bf16* __restrict__ C) {
    __shared__ __bf16 Bs[16][64 * 32];     // [kt][col][8k-chunks] = 64 KB
    const int t = threadIdx.x;
    const int w = t >> 6, l = t & 63;
    const int ml = l & 15, quad = l >> 4;
    const int row0 = blockIdx.x * 128;
    const int col0 = blockIdx.y * 64;

    // ---- stage B once: thread covers (col = w*16 + l>>2, j = l&3), all kt.
    // Per wave-instr: 64 lanes x 16 B = cols [w*16, w*16+16) of one kt,
    // LDS dest contiguous 1024 B at Bs[kt] + w*16*32 elems.
    {
        const int c = w * 16 + (l >> 2);
        const int j = l & 3;
        const __bf16* src = Bt + (size_t)(col0 + c) * NFEAT + j * 8;
        #pragma unroll
        for (int kt = 0; kt < 16; kt++)
            GLOAD_LDS16(src + kt * 32, &Bs[kt][(size_t)(w * 16) * 32]);
    }

    // ---- A pointers (rows clamped into [0, N_NODES))
    const int r0c = min(row0 + w * 32 + ml,      N_NODES - 1);
    const int r1c = min(row0 + w * 32 + 16 + ml, N_NODES - 1);
    const float* a0p = X + (size_t)r0c * NFEAT + quad * 8;
    const float* a1p = X + (size_t)r1c * NFEAT + quad * 8;

    f32x4 acc[2][4] = {};

    // prefetch kt = 0
    float4 p00 = *(const float4*)(a0p);
    float4 p01 = *(const float4*)(a0p + 4);
    float4 p10 = *(const float4*)(a1p);
    float4 p11 = *(const float4*)(a1p + 4);

    __syncthreads();   // the only barrier: B slab resident from here on

    for (int kt = 0; kt < 16; kt++) {
        bf16x8 af0 = pack8(p00, p01);
        bf16x8 af1 = pack8(p10, p11);
        if (kt < 15) {                 // prefetch kt+1 while computing kt
            const int o = (kt + 1) * 32;
            p00 = *(const float4*)(a0p + o);
            p01 = *(const float4*)(a0p + o + 4);
            p10 = *(const float4*)(a1p + o);
            p11 = *(const float4*)(a1p + o + 4);
        }
        bf16x8 bfr[4];
        #pragma unroll
        for (int ni = 0; ni < 4; ni++)
            bfr[ni] = *(const bf16x8*)(&Bs[kt][(ni * 16 + ml) * 32 + quad * 8]);
        #pragma unroll
        for (int ni = 0; ni < 4; ni++)
            acc[0][ni] = __builtin_amdgcn_mfma_f32_16x16x32_bf16(
                af0, bfr[ni], acc[0][ni], 0, 0, 0);
        #pragma unroll
        for (int ni = 0; ni < 4; ni++)
            acc[1][ni] = __builtin_amdgcn_mfma_f32_16x16x32_bf16(
                af1, bfr[ni], acc[1][ni], 0, 0, 0);
    }

    // C/D layout: col = lane&15, row = quad*4 + reg. Pad rows written (ws).
    #pragma unroll
    for (int mi = 0; mi < 2; mi++) {
        int gr = row0 + w * 32 + mi * 16 + quad * 4;
        #pragma unroll
        for (int ni = 0; ni < 4; ni++) {
            int gc = col0 + ni * 16 + ml;
            #pragma unroll
            for (int r2 = 0; r2 < 4; r2++)
                C[(size_t)(gr + r2) * NHID + gc] = (__bf16)acc[mi][ni][r2];
        }
    }
}

// ---------------------------------------------------------------------------
// GEMM2, barrier-free K-loop: C[MP][64] bf16 = h1[MP][256] @ w2t[64][256]^T.
// Whole w2t (32 KB) staged to LDS once in [kt][col][32] layout; A fragments
// direct from global (h1 is L2/L3-hot, pad rows zeroed). 64 rows/block,
// wave = 16 rows x 64 cols. Grid 782.
// ---------------------------------------------------------------------------
__global__ __launch_bounds__(256) void gemm2_nb(const __bf16* __restrict__ A,
                                                const __bf16* __restrict__ Bt,
                                                __bf16* __restrict__ C) {
    __shared__ __bf16 Bs[8][64 * 32];      // 32 KB, full w2t
    const int t = threadIdx.x;
    const int w = t >> 6, l = t & 63;
    const int ml = l & 15, quad = l >> 4;
    const int row0 = blockIdx.x * 64;

    {
        const int c = w * 16 + (l >> 2);
        const int j = l & 3;
        const __bf16* src = Bt + (size_t)c * NHID + j * 8;
        #pragma unroll
        for (int kt = 0; kt < 8; kt++)
            GLOAD_LDS16(src + kt * 32, &Bs[kt][(size_t)(w * 16) * 32]);
    }

    const __bf16* ap = A + (size_t)(row0 + w * 16 + ml) * NHID + quad * 8;
    bf16x8 pa = *(const bf16x8*)(ap);

    f32x4 acc[4] = {};
    __syncthreads();   // the only barrier

    for (int kt = 0; kt < 8; kt++) {
        bf16x8 af = pa;
        if (kt < 7) pa = *(const bf16x8*)(ap + (kt + 1) * 32);
        bf16x8 bfr[4];
        #pragma unroll
        for (int ni = 0; ni < 4; ni++)
            bfr[ni] = *(const bf16x8*)(&Bs[kt][(ni * 16 + ml) * 32 + quad * 8]);
        #pragma unroll
        for (int ni = 0; ni < 4; ni++)
            acc[ni] = __builtin_amdgcn_mfma_f32_16x16x32_bf16(
                af, bfr[ni], acc[ni], 0, 0, 0);
    }

    #pragma unroll
    for (int ni = 0; ni < 4; ni++) {
        int gc = ni * 16 + ml;
        #pragma unroll
        for (int r2 = 0; r2 < 4; r2++) {
            int gr = row0 + w * 16 + quad * 4 + r2;
            C[(size_t)gr * NOUT + gc] = (__bf16)acc[ni][r2];
        }
    }
}

// ---------------------------------------------------------------------------
// SpMM1 + bias + ReLU: one wave per node. Half-wave (32 lanes) per edge,
// 16 B/lane (8 bf16 feats). Unrolled x4 -> 8 edges in flight per wave.
// ---------------------------------------------------------------------------
__global__ __launch_bounds__(256) void spmm1_wave(const __bf16* __restrict__ h0,
                                                  const float* __restrict__ ew,
                                                  const int* __restrict__ col,
                                                  const int* __restrict__ rp,
                                                  const float* __restrict__ b1,
                                                  __bf16* __restrict__ h1) {
    const int n    = blockIdx.x * 4 + (threadIdx.x >> 6);
    const int lane = threadIdx.x & 63;
    const int half = lane >> 5;
    const int fl   = lane & 31;       // 8 bf16 feats per lane
    const int s = rp[n], e = rp[n + 1];

    float acc[8] = {};
    int i = s + half;
    for (; i + 6 < e; i += 8) {
        int   c0 = col[i],     c1 = col[i + 2], c2 = col[i + 4], c3 = col[i + 6];
        float w0 = ew[i],      w1 = ew[i + 2],  w2 = ew[i + 4],  w3 = ew[i + 6];
        uint4 v0 = *(const uint4*)(h0 + (size_t)c0 * NHID + fl * 8);
        uint4 v1 = *(const uint4*)(h0 + (size_t)c1 * NHID + fl * 8);
        uint4 v2 = *(const uint4*)(h0 + (size_t)c2 * NHID + fl * 8);
        uint4 v3 = *(const uint4*)(h0 + (size_t)c3 * NHID + fl * 8);
        const unsigned* p0 = &v0.x; const unsigned* p1 = &v1.x;
        const unsigned* p2 = &v2.x; const unsigned* p3 = &v3.x;
        #pragma unroll
        for (int j = 0; j < 4; j++) {
            acc[2*j+0] += w0 * __builtin_bit_cast(float, p0[j] << 16)
                        + w1 * __builtin_bit_cast(float, p1[j] << 16)
                        + w2 * __builtin_bit_cast(float, p2[j] << 16)
                        + w3 * __builtin_bit_cast(float, p3[j] << 16);
            acc[2*j+1] += w0 * __builtin_bit_cast(float, p0[j] & 0xffff0000u)
                        + w1 * __builtin_bit_cast(float, p1[j] & 0xffff0000u)
                        + w2 * __builtin_bit_cast(float, p2[j] & 0xffff0000u)
                        + w3 * __builtin_bit_cast(float, p3[j] & 0xffff0000u);
        }
    }
    for (; i < e; i += 2) {
        int   c0 = col[i];
        float w0 = ew[i];
        uint4 v0 = *(const uint4*)(h0 + (size_t)c0 * NHID + fl * 8);
        const unsigned* p0 = &v0.x;
        #pragma unroll
        for (int j = 0; j < 4; j++) {
            acc[2*j+0] += w0 * __builtin_bit_cast(float, p0[j] << 16);
            acc[2*j+1] += w0 * __builtin_bit_cast(float, p0[j] & 0xffff0000u);
        }
    }

    #pragma unroll
    for (int j = 0; j < 8; j++)
        acc[j] += __shfl_down(acc[j], 32, 64);

    if (half == 0) {
        unsigned short u[8];
        #pragma unroll
        for (int j = 0; j < 8; j++) {
            float v = acc[j] + b1[fl * 8 + j];
            u[j] = f2bf(v > 0.f ? v : 0.f);
        }
        uint4 o;
        o.x = (unsigned)u[0] | ((unsigned)u[1] << 16);
        o.y = (unsigned)u[2] | ((unsigned)u[3] << 16);
        o.z = (unsigned)u[4] | ((unsigned)u[5] << 16);
        o.w = (unsigned)u[6] | ((unsigned)u[7] << 16);
        *(uint4*)(h1 + (size_t)n * NHID + fl * 8) = o;
    }
}

// ---------------------------------------------------------------------------
// SpMM2 + bias: one wave per node, h2 is bf16 [MP][64]. Quarter-wave (16
// lanes x uint2 = 4 bf16) per edge -> 4 edges per load instr, unroll x2.
// ---------------------------------------------------------------------------
__global__ __launch_bounds__(256) void spmm2_wave(const __bf16* __restrict__ h2,
                                                  const float* __restrict__ ew,
                                                  const int* __restrict__ col,
                                                  const int* __restrict__ rp,
                                                  const float* __restrict__ b2,
                                                  float* __restrict__ out) {
    const int n    = blockIdx.x * 4 + (threadIdx.x >> 6);
    const int lane = threadIdx.x & 63;
    const int g    = lane >> 4;       // edge group 0..3
    const int fl   = lane & 15;       // 4 feats per lane
    const int s = rp[n], e = rp[n + 1];

    float a0 = 0.f, a1 = 0.f, a2 = 0.f, a3 = 0.f;
    int i = s + g;
    for (; i + 4 < e; i += 8) {
        int   c0 = col[i];     float w0 = ew[i];
        int   c1 = col[i + 4]; float w1 = ew[i + 4];
        uint2 v0 = *(const uint2*)(h2 + (size_t)c0 * NOUT + fl * 4);
        uint2 v1 = *(const uint2*)(h2 + (size_t)c1 * NOUT + fl * 4);
        a0 += w0 * __builtin_bit_cast(float, v0.x << 16)
            + w1 * __builtin_bit_cast(float, v1.x << 16);
        a1 += w0 * __builtin_bit_cast(float, v0.x & 0xffff0000u)
            + w1 * __builtin_bit_cast(float, v1.x & 0xffff0000u);
        a2 += w0 * __builtin_bit_cast(float, v0.y << 16)
            + w1 * __builtin_bit_cast(float, v1.y << 16);
        a3 += w0 * __builtin_bit_cast(float, v0.y & 0xffff0000u)
            + w1 * __builtin_bit_cast(float, v1.y & 0xffff0000u);
    }
    for (; i < e; i += 4) {
        int   c0 = col[i]; float w0 = ew[i];
        uint2 v0 = *(const uint2*)(h2 + (size_t)c0 * NOUT + fl * 4);
        a0 += w0 * __builtin_bit_cast(float, v0.x << 16);
        a1 += w0 * __builtin_bit_cast(float, v0.x & 0xffff0000u);
        a2 += w0 * __builtin_bit_cast(float, v0.y << 16);
        a3 += w0 * __builtin_bit_cast(float, v0.y & 0xffff0000u);
    }

    a0 += __shfl_down(a0, 32, 64); a1 += __shfl_down(a1, 32, 64);
    a2 += __shfl_down(a2, 32, 64); a3 += __shfl_down(a3, 32, 64);
    a0 += __shfl_down(a0, 16, 64); a1 += __shfl_down(a1, 16, 64);
    a2 += __shfl_down(a2, 16, 64); a3 += __shfl_down(a3, 16, 64);

    if (lane < 16) {
        float4 bb = *(const float4*)(b2 + fl * 4);
        float4 o = make_float4(a0 + bb.x, a1 + bb.y, a2 + bb.z, a3 + bb.w);
        *(float4*)(out + (size_t)n * NOUT + fl * 4) = o;
    }
}

// ---------------------------------------------------------------------------
extern "C" void kernel_launch(void* const* d_in, const int* in_sizes, int n_in,
                              void* d_out, int out_size, void* d_ws, size_t ws_size,
                              hipStream_t stream) {
    const float* x   = (const float*)d_in[0];
    const float* w1  = (const float*)d_in[1];
    const float* b1  = (const float*)d_in[2];
    const float* w2  = (const float*)d_in[3];
    const float* b2  = (const float*)d_in[4];
    const float* ew  = (const float*)d_in[5];
    const int*   row = (const int*)d_in[6];
    const int*   col = (const int*)d_in[7];
    float* out = (float*)d_out;

    char* ws = (char*)d_ws;
    size_t off = 0;
    int*    rp  = (int*)(ws + off);   off += 256 * 1024;
    __bf16* w1t = (__bf16*)(ws + off); off += (size_t)NHID * NFEAT * 2;   // 256 KB
    __bf16* w2t = (__bf16*)(ws + off); off += (size_t)NOUT * NHID * 2;    // 32 KB
    __bf16* h0  = (__bf16*)(ws + off); off += (size_t)MP * NHID * 2;      // 25.6 MB
    __bf16* h1  = (__bf16*)(ws + off); off += (size_t)MP * NHID * 2;      // 25.6 MB
    __bf16* h2  = (__bf16*)(ws + off);                                     // 6.4 MB

    prep<<<820, 256, 0, stream>>>(row, rp, w1, w1t, w2, w2t, h1);

    // layer 1 dense (fused fp32->bf16 on A): h0 = bf16(x) @ w1
    gemm1_nb<<<dim3(MP / 128, 4), 256, 0, stream>>>(x, w1t, h0);

    // layer 1 sparse: h1 = relu(adj @ h0 + b1)
    spmm1_wave<<<N_NODES / 4, 256, 0, stream>>>(h0, ew, col, rp, b1, h1);

    // layer 2 dense: h2 = h1 @ w2
    gemm2_nb<<<MP / 64, 256, 0, stream>>>(h1, w2t, h2);

    // layer 2 sparse: out = adj @ h2 + b2
    spmm2_wave<<<N_NODES / 4, 256, 0, stream>>>(h2, ew, col, rp, b2, out);
}

// Round 9
// 301.180 us; speedup vs baseline: 1.0368x; 1.0368x over previous
//
#include <hip/hip_runtime.h>

#define N_NODES 50000
#define MP      50048        // N_NODES padded to multiple of 128
#define N_EDGES 800000
#define NFEAT   512
#define NHID    256
#define NOUT    64

typedef __bf16 bf16x8 __attribute__((ext_vector_type(8)));
typedef float  f32x4  __attribute__((ext_vector_type(4)));

// async global->LDS, 16B per lane. LDS dest = wave-uniform base + lane*16.
#define GLOAD_LDS16(g, l) __builtin_amdgcn_global_load_lds(                    \
    (const __attribute__((address_space(1))) void*)(g),                        \
    (__attribute__((address_space(3))) void*)(l), 16, 0, 0)

__device__ __forceinline__ unsigned short f2bf(float f) {
    __bf16 b = (__bf16)f;                       // RNE
    return __builtin_bit_cast(unsigned short, b);
}

__device__ __forceinline__ bf16x8 pack8(float4 a, float4 b) {
    uint4 o;
    o.x = (unsigned)f2bf(a.x) | ((unsigned)f2bf(a.y) << 16);
    o.y = (unsigned)f2bf(a.z) | ((unsigned)f2bf(a.w) << 16);
    o.z = (unsigned)f2bf(b.x) | ((unsigned)f2bf(b.y) << 16);
    o.w = (unsigned)f2bf(b.z) | ((unsigned)f2bf(b.w) << 16);
    return __builtin_bit_cast(bf16x8, o);
}

// ---------------------------------------------------------------------------
// prep: fused rowptr + w1 transpose + w2 transpose + h1 pad zero. 820 blocks.
// ---------------------------------------------------------------------------
__global__ __launch_bounds__(256) void prep(const int* __restrict__ row,
                                            int* __restrict__ rp,
                                            const float* __restrict__ w1,
                                            __bf16* __restrict__ w1t,
                                            const float* __restrict__ w2,
                                            __bf16* __restrict__ w2t,
                                            __bf16* __restrict__ h1) {
    const int b = blockIdx.x, t = threadIdx.x;
    if (b < 196) {
        int r = b * 256 + t;
        if (r <= N_NODES) {
            int lo = 0, hi = N_EDGES;
            while (lo < hi) {
                int mid = (lo + hi) >> 1;
                if (row[mid] < r) lo = mid + 1; else hi = mid;
            }
            rp[r] = lo;
        }
    } else if (b < 708) {
        int o = (b - 196) * 256 + t;          // n = o>>9, k = o&511
        w1t[o] = (__bf16)w1[(size_t)(o & 511) * NHID + (o >> 9)];
    } else if (b < 772) {
        int o = (b - 708) * 256 + t;          // n = o>>8, k = o&255
        w2t[o] = (__bf16)w2[(size_t)(o & 255) * NOUT + (o >> 8)];
    } else {
        int o = (b - 772) * 256 + t;
        h1[(size_t)N_NODES * NHID + o] = (__bf16)0.f;
    }
}

// ---------------------------------------------------------------------------
// GEMM1, barrier-free K-loop: C[MP][256] bf16 = bf16(X fp32) @ w1t[256][512]^T
// Block = 128 rows x 64 cols, 4 waves (32 rows each). B-slab (64 KB) staged
// to LDS once in [kt][col][32] layout; single barrier; 16 K-iters with A
// direct-to-register (1-iter prefetch), ds_read B, MFMA — no barriers in loop.
// GRID SWIZZLE (R9): 1D grid, rowblk = bid>>2, colblk = bid&3 — the 4
// column-blocks sharing an X row-tile are dispatch-adjacent, so X re-reads
// hit L3 (reuse distance ~3 blocks) and HBM fetches X once.
// ---------------------------------------------------------------------------
__global__ __launch_bounds__(256) void gemm1_nb(const float* __restrict__ X,
                                                const __bf16* __restrict__ Bt,
                                                __bf16* __restrict__ C) {
    __shared__ __bf16 Bs[16][64 * 32];     // [kt][col][8k-chunks] = 64 KB
    const int t = threadIdx.x;
    const int w = t >> 6, l = t & 63;
    const int ml = l & 15, quad = l >> 4;
    const int row0 = (blockIdx.x >> 2) * 128;
    const int col0 = (blockIdx.x & 3) * 64;

    // ---- stage B once: thread covers (col = w*16 + l>>2, j = l&3), all kt.
    {
        const int c = w * 16 + (l >> 2);
        const int j = l & 3;
        const __bf16* src = Bt + (size_t)(col0 + c) * NFEAT + j * 8;
        #pragma unroll
        for (int kt = 0; kt < 16; kt++)
            GLOAD_LDS16(src + kt * 32, &Bs[kt][(size_t)(w * 16) * 32]);
    }

    // ---- A pointers (rows clamped into [0, N_NODES))
    const int r0c = min(row0 + w * 32 + ml,      N_NODES - 1);
    const int r1c = min(row0 + w * 32 + 16 + ml, N_NODES - 1);
    const float* a0p = X + (size_t)r0c * NFEAT + quad * 8;
    const float* a1p = X + (size_t)r1c * NFEAT + quad * 8;

    f32x4 acc[2][4] = {};

    // prefetch kt = 0
    float4 p00 = *(const float4*)(a0p);
    float4 p01 = *(const float4*)(a0p + 4);
    float4 p10 = *(const float4*)(a1p);
    float4 p11 = *(const float4*)(a1p + 4);

    __syncthreads();   // the only barrier: B slab resident from here on

    for (int kt = 0; kt < 16; kt++) {
        bf16x8 af0 = pack8(p00, p01);
        bf16x8 af1 = pack8(p10, p11);
        if (kt < 15) {                 // prefetch kt+1 while computing kt
            const int o = (kt + 1) * 32;
            p00 = *(const float4*)(a0p + o);
            p01 = *(const float4*)(a0p + o + 4);
            p10 = *(const float4*)(a1p + o);
            p11 = *(const float4*)(a1p + o + 4);
        }
        bf16x8 bfr[4];
        #pragma unroll
        for (int ni = 0; ni < 4; ni++)
            bfr[ni] = *(const bf16x8*)(&Bs[kt][(ni * 16 + ml) * 32 + quad * 8]);
        #pragma unroll
        for (int ni = 0; ni < 4; ni++)
            acc[0][ni] = __builtin_amdgcn_mfma_f32_16x16x32_bf16(
                af0, bfr[ni], acc[0][ni], 0, 0, 0);
        #pragma unroll
        for (int ni = 0; ni < 4; ni++)
            acc[1][ni] = __builtin_amdgcn_mfma_f32_16x16x32_bf16(
                af1, bfr[ni], acc[1][ni], 0, 0, 0);
    }

    // C/D layout: col = lane&15, row = quad*4 + reg. Pad rows written (ws).
    #pragma unroll
    for (int mi = 0; mi < 2; mi++) {
        int gr = row0 + w * 32 + mi * 16 + quad * 4;
        #pragma unroll
        for (int ni = 0; ni < 4; ni++) {
            int gc = col0 + ni * 16 + ml;
            #pragma unroll
            for (int r2 = 0; r2 < 4; r2++)
                C[(size_t)(gr + r2) * NHID + gc] = (__bf16)acc[mi][ni][r2];
        }
    }
}

// ---------------------------------------------------------------------------
// GEMM2, barrier-free K-loop: C[MP][64] bf16 = h1[MP][256] @ w2t[64][256]^T.
// Whole w2t (32 KB) staged to LDS once in [kt][col][32] layout; A fragments
// direct from global (h1 is L2/L3-hot, pad rows zeroed). 64 rows/block.
// ---------------------------------------------------------------------------
__global__ __launch_bounds__(256) void gemm2_nb(const __bf16* __restrict__ A,
                                                const __bf16* __restrict__ Bt,
                                                __bf16* __restrict__ C) {
    __shared__ __bf16 Bs[8][64 * 32];      // 32 KB, full w2t
    const int t = threadIdx.x;
    const int w = t >> 6, l = t & 63;
    const int ml = l & 15, quad = l >> 4;
    const int row0 = blockIdx.x * 64;

    {
        const int c = w * 16 + (l >> 2);
        const int j = l & 3;
        const __bf16* src = Bt + (size_t)c * NHID + j * 8;
        #pragma unroll
        for (int kt = 0; kt < 8; kt++)
            GLOAD_LDS16(src + kt * 32, &Bs[kt][(size_t)(w * 16) * 32]);
    }

    const __bf16* ap = A + (size_t)(row0 + w * 16 + ml) * NHID + quad * 8;
    bf16x8 pa = *(const bf16x8*)(ap);

    f32x4 acc[4] = {};
    __syncthreads();   // the only barrier

    for (int kt = 0; kt < 8; kt++) {
        bf16x8 af = pa;
        if (kt < 7) pa = *(const bf16x8*)(ap + (kt + 1) * 32);
        bf16x8 bfr[4];
        #pragma unroll
        for (int ni = 0; ni < 4; ni++)
            bfr[ni] = *(const bf16x8*)(&Bs[kt][(ni * 16 + ml) * 32 + quad * 8]);
        #pragma unroll
        for (int ni = 0; ni < 4; ni++)
            acc[ni] = __builtin_amdgcn_mfma_f32_16x16x32_bf16(
                af, bfr[ni], acc[ni], 0, 0, 0);
    }

    #pragma unroll
    for (int ni = 0; ni < 4; ni++) {
        int gc = ni * 16 + ml;
        #pragma unroll
        for (int r2 = 0; r2 < 4; r2++) {
            int gr = row0 + w * 16 + quad * 4 + r2;
            C[(size_t)gr * NOUT + gc] = (__bf16)acc[ni][r2];
        }
    }
}

// ---------------------------------------------------------------------------
// SpMM1 + bias + ReLU: one wave per node. Half-wave (32 lanes) per edge,
// 16 B/lane (8 bf16 feats). Unrolled x4 -> 8 edges in flight per wave.
// ---------------------------------------------------------------------------
__global__ __launch_bounds__(256) void spmm1_wave(const __bf16* __restrict__ h0,
                                                  const float* __restrict__ ew,
                                                  const int* __restrict__ col,
                                                  const int* __restrict__ rp,
                                                  const float* __restrict__ b1,
                                                  __bf16* __restrict__ h1) {
    const int n    = blockIdx.x * 4 + (threadIdx.x >> 6);
    const int lane = threadIdx.x & 63;
    const int half = lane >> 5;
    const int fl   = lane & 31;       // 8 bf16 feats per lane
    const int s = rp[n], e = rp[n + 1];

    float acc[8] = {};
    int i = s + half;
    for (; i + 6 < e; i += 8) {
        int   c0 = col[i],     c1 = col[i + 2], c2 = col[i + 4], c3 = col[i + 6];
        float w0 = ew[i],      w1 = ew[i + 2],  w2 = ew[i + 4],  w3 = ew[i + 6];
        uint4 v0 = *(const uint4*)(h0 + (size_t)c0 * NHID + fl * 8);
        uint4 v1 = *(const uint4*)(h0 + (size_t)c1 * NHID + fl * 8);
        uint4 v2 = *(const uint4*)(h0 + (size_t)c2 * NHID + fl * 8);
        uint4 v3 = *(const uint4*)(h0 + (size_t)c3 * NHID + fl * 8);
        const unsigned* p0 = &v0.x; const unsigned* p1 = &v1.x;
        const unsigned* p2 = &v2.x; const unsigned* p3 = &v3.x;
        #pragma unroll
        for (int j = 0; j < 4; j++) {
            acc[2*j+0] += w0 * __builtin_bit_cast(float, p0[j] << 16)
                        + w1 * __builtin_bit_cast(float, p1[j] << 16)
                        + w2 * __builtin_bit_cast(float, p2[j] << 16)
                        + w3 * __builtin_bit_cast(float, p3[j] << 16);
            acc[2*j+1] += w0 * __builtin_bit_cast(float, p0[j] & 0xffff0000u)
                        + w1 * __builtin_bit_cast(float, p1[j] & 0xffff0000u)
                        + w2 * __builtin_bit_cast(float, p2[j] & 0xffff0000u)
                        + w3 * __builtin_bit_cast(float, p3[j] & 0xffff0000u);
        }
    }
    for (; i < e; i += 2) {
        int   c0 = col[i];
        float w0 = ew[i];
        uint4 v0 = *(const uint4*)(h0 + (size_t)c0 * NHID + fl * 8);
        const unsigned* p0 = &v0.x;
        #pragma unroll
        for (int j = 0; j < 4; j++) {
            acc[2*j+0] += w0 * __builtin_bit_cast(float, p0[j] << 16);
            acc[2*j+1] += w0 * __builtin_bit_cast(float, p0[j] & 0xffff0000u);
        }
    }

    #pragma unroll
    for (int j = 0; j < 8; j++)
        acc[j] += __shfl_down(acc[j], 32, 64);

    if (half == 0) {
        unsigned short u[8];
        #pragma unroll
        for (int j = 0; j < 8; j++) {
            float v = acc[j] + b1[fl * 8 + j];
            u[j] = f2bf(v > 0.f ? v : 0.f);
        }
        uint4 o;
        o.x = (unsigned)u[0] | ((unsigned)u[1] << 16);
        o.y = (unsigned)u[2] | ((unsigned)u[3] << 16);
        o.z = (unsigned)u[4] | ((unsigned)u[5] << 16);
        o.w = (unsigned)u[6] | ((unsigned)u[7] << 16);
        *(uint4*)(h1 + (size_t)n * NHID + fl * 8) = o;
    }
}

// ---------------------------------------------------------------------------
// SpMM2 + bias: one wave per node, h2 is bf16 [MP][64]. Quarter-wave (16
// lanes x uint2 = 4 bf16) per edge -> 4 edges per load instr, unroll x2.
// ---------------------------------------------------------------------------
__global__ __launch_bounds__(256) void spmm2_wave(const __bf16* __restrict__ h2,
                                                  const float* __restrict__ ew,
                                                  const int* __restrict__ col,
                                                  const int* __restrict__ rp,
                                                  const float* __restrict__ b2,
                                                  float* __restrict__ out) {
    const int n    = blockIdx.x * 4 + (threadIdx.x >> 6);
    const int lane = threadIdx.x & 63;
    const int g    = lane >> 4;       // edge group 0..3
    const int fl   = lane & 15;       // 4 feats per lane
    const int s = rp[n], e = rp[n + 1];

    float a0 = 0.f, a1 = 0.f, a2 = 0.f, a3 = 0.f;
    int i = s + g;
    for (; i + 4 < e; i += 8) {
        int   c0 = col[i];     float w0 = ew[i];
        int   c1 = col[i + 4]; float w1 = ew[i + 4];
        uint2 v0 = *(const uint2*)(h2 + (size_t)c0 * NOUT + fl * 4);
        uint2 v1 = *(const uint2*)(h2 + (size_t)c1 * NOUT + fl * 4);
        a0 += w0 * __builtin_bit_cast(float, v0.x << 16)
            + w1 * __builtin_bit_cast(float, v1.x << 16);
        a1 += w0 * __builtin_bit_cast(float, v0.x & 0xffff0000u)
            + w1 * __builtin_bit_cast(float, v1.x & 0xffff0000u);
        a2 += w0 * __builtin_bit_cast(float, v0.y << 16)
            + w1 * __builtin_bit_cast(float, v1.y << 16);
        a3 += w0 * __builtin_bit_cast(float, v0.y & 0xffff0000u)
            + w1 * __builtin_bit_cast(float, v1.y & 0xffff0000u);
    }
    for (; i < e; i += 4) {
        int   c0 = col[i]; float w0 = ew[i];
        uint2 v0 = *(const uint2*)(h2 + (size_t)c0 * NOUT + fl * 4);
        a0 += w0 * __builtin_bit_cast(float, v0.x << 16);
        a1 += w0 * __builtin_bit_cast(float, v0.x & 0xffff0000u);
        a2 += w0 * __builtin_bit_cast(float, v0.y << 16);
        a3 += w0 * __builtin_bit_cast(float, v0.y & 0xffff0000u);
    }

    a0 += __shfl_down(a0, 32, 64); a1 += __shfl_down(a1, 32, 64);
    a2 += __shfl_down(a2, 32, 64); a3 += __shfl_down(a3, 32, 64);
    a0 += __shfl_down(a0, 16, 64); a1 += __shfl_down(a1, 16, 64);
    a2 += __shfl_down(a2, 16, 64); a3 += __shfl_down(a3, 16, 64);

    if (lane < 16) {
        float4 bb = *(const float4*)(b2 + fl * 4);
        float4 o = make_float4(a0 + bb.x, a1 + bb.y, a2 + bb.z, a3 + bb.w);
        *(float4*)(out + (size_t)n * NOUT + fl * 4) = o;
    }
}

// ---------------------------------------------------------------------------
extern "C" void kernel_launch(void* const* d_in, const int* in_sizes, int n_in,
                              void* d_out, int out_size, void* d_ws, size_t ws_size,
                              hipStream_t stream) {
    const float* x   = (const float*)d_in[0];
    const float* w1  = (const float*)d_in[1];
    const float* b1  = (const float*)d_in[2];
    const float* w2  = (const float*)d_in[3];
    const float* b2  = (const float*)d_in[4];
    const float* ew  = (const float*)d_in[5];
    const int*   row = (const int*)d_in[6];
    const int*   col = (const int*)d_in[7];
    float* out = (float*)d_out;

    char* ws = (char*)d_ws;
    size_t off = 0;
    int*    rp  = (int*)(ws + off);   off += 256 * 1024;
    __bf16* w1t = (__bf16*)(ws + off); off += (size_t)NHID * NFEAT * 2;   // 256 KB
    __bf16* w2t = (__bf16*)(ws + off); off += (size_t)NOUT * NHID * 2;    // 32 KB
    __bf16* h0  = (__bf16*)(ws + off); off += (size_t)MP * NHID * 2;      // 25.6 MB
    __bf16* h1  = (__bf16*)(ws + off); off += (size_t)MP * NHID * 2;      // 25.6 MB
    __bf16* h2  = (__bf16*)(ws + off);                                     // 6.4 MB

    prep<<<820, 256, 0, stream>>>(row, rp, w1, w1t, w2, w2t, h1);

    // layer 1 dense (fused fp32->bf16 on A): h0 = bf16(x) @ w1
    // swizzled 1D grid: rowblk = bid>>2, colblk = bid&3
    gemm1_nb<<<(MP / 128) * 4, 256, 0, stream>>>(x, w1t, h0);

    // layer 1 sparse: h1 = relu(adj @ h0 + b1)
    spmm1_wave<<<N_NODES / 4, 256, 0, stream>>>(h0, ew, col, rp, b1, h1);

    // layer 2 dense: h2 = h1 @ w2
    gemm2_nb<<<MP / 64, 256, 0, stream>>>(h1, w2t, h2);

    // layer 2 sparse: out = adj @ h2 + b2
    spmm2_wave<<<N_NODES / 4, 256, 0, stream>>>(h2, ew, col, rp, b2, out);
}